// Round 2
// baseline (920.814 us; speedup 1.0000x reference)
//
#include <hip/hip_runtime.h>
#include <stdint.h>

#define N_PTS 8192
#define N_B 8
#define NGROUP 512
#define GSIZE 32
#define BIGF 1e10f

#define K1_THREADS 512
#define K1_PPT (N_PTS / K1_THREADS)   // 16
#define K1_WAVES (K1_THREADS / 64)    // 8

#define K2_THREADS 256
#define K2_PPT (N_PTS / K2_THREADS)   // 32
#define K2_WAVES (K2_THREADS / 64)    // 4

// Exact (no-FMA) squared distance in numpy's evaluation order: (dx^2 + dy^2) + dz^2
// (matches np.sum((pts - centroid)**2, -1): separate square op, left-assoc reduce)
__device__ __forceinline__ float sq_dist(float x, float y, float z,
                                         float cx, float cy, float cz) {
    float dx = __fsub_rn(x, cx);
    float dy = __fsub_rn(y, cy);
    float dz = __fsub_rn(z, cz);
    return __fadd_rn(__fadd_rn(__fmul_rn(dx, dx), __fmul_rn(dy, dy)), __fmul_rn(dz, dz));
}

// order-preserving float->uint transform (handles possible tiny-negative d2)
__device__ __forceinline__ unsigned fxform(unsigned u) {
    return u ^ (unsigned)(((int)u >> 31) | 0x80000000);
}

// ---------------- Kernel 1: farthest point sampling, one block per batch ---------------
extern "C" __global__ __launch_bounds__(K1_THREADS) void fps_kernel(
    const float* __restrict__ xyz, int* __restrict__ fps_idx)
{
    const int b   = blockIdx.x;
    const int tid = threadIdx.x;
    const float* base = xyz + (size_t)b * N_PTS * 6;

    float px[K1_PPT], py[K1_PPT], pz[K1_PPT], dd[K1_PPT];
#pragma unroll
    for (int i = 0; i < K1_PPT; ++i) {
        int p = tid + i * K1_THREADS;
        px[i] = base[p * 6 + 0];
        py[i] = base[p * 6 + 1];
        pz[i] = base[p * 6 + 2];
        dd[i] = BIGF;
    }

    __shared__ unsigned long long part[2][K1_WAVES];

    const int wid  = tid >> 6;
    const int lane = tid & 63;
    int cur = 0;

    for (int it = 0; it < NGROUP; ++it) {
        if (tid == 0) fps_idx[b * NGROUP + it] = cur;
        if (it == NGROUP - 1) break;

        // centroid = pts[cur] (wave-uniform scalar load)
        const int c = __builtin_amdgcn_readfirstlane(cur);
        const float cx = base[c * 6 + 0];
        const float cy = base[c * 6 + 1];
        const float cz = base[c * 6 + 2];

        // min-update + local argmax (first-max tie-break: strict >, ascending p)
        float bestd = -1.0f;
        int   bestp = 0;
#pragma unroll
        for (int i = 0; i < K1_PPT; ++i) {
            float d = sq_dist(px[i], py[i], pz[i], cx, cy, cz);
            dd[i] = fminf(dd[i], d);
            if (dd[i] > bestd) { bestd = dd[i]; bestp = tid + i * K1_THREADS; }
        }

        // pack: max key == max dist, ties -> smaller index (via complement)
        unsigned long long key =
            ((unsigned long long)__float_as_uint(bestd) << 32)
          | (unsigned long long)(0xFFFFFFFFu - (unsigned)bestp);

#pragma unroll
        for (int off = 32; off >= 1; off >>= 1) {
            unsigned long long o = __shfl_xor(key, off, 64);
            if (o > key) key = o;
        }
        if (lane == 0) part[it & 1][wid] = key;
        __syncthreads();
#pragma unroll
        for (int w = 0; w < K1_WAVES; ++w) {
            unsigned long long o = part[it & 1][w];
            if (o > key) key = o;
        }
        cur = (int)(0xFFFFFFFFu - (unsigned)(key & 0xFFFFFFFFull));
    }
}

// ---------------- Kernel 2: 32-NN per (batch, group) + gather/write outputs -----------
extern "C" __global__ __launch_bounds__(K2_THREADS) void knn_kernel(
    const float* __restrict__ xyz, const int* __restrict__ fps_idx,
    float* __restrict__ out)
{
    const int bg  = blockIdx.x;
    const int b   = bg >> 9;          // / NGROUP
    const int g   = bg & (NGROUP - 1);
    const int tid = threadIdx.x;
    const float* base = xyz + (size_t)b * N_PTS * 6;

    const int q  = fps_idx[b * NGROUP + g];
    const int qq = __builtin_amdgcn_readfirstlane(q);
    const float cx = base[qq * 6 + 0];
    const float cy = base[qq * 6 + 1];
    const float cz = base[qq * 6 + 2];
    // ||c||^2: np.sum(center**2, -1) — separate square, left-assoc add, NO FMA
    const float cn = __fadd_rn(__fadd_rn(__fmul_rn(cx, cx), __fmul_rn(cy, cy)),
                               __fmul_rn(cz, cz));

    unsigned long long keys[K2_PPT];
    unsigned long long lmin = ~0ull;
#pragma unroll
    for (int i = 0; i < K2_PPT; ++i) {
        int p = tid + i * K2_THREADS;
        float x = base[p * 6 + 0];
        float y = base[p * 6 + 1];
        float z = base[p * 6 + 2];
        // ||x||^2: NO FMA (separate numpy op)
        float xn  = __fadd_rn(__fadd_rn(__fmul_rn(x, x), __fmul_rn(y, y)), __fmul_rn(z, z));
        // einsum dot: BLAS/XLA contraction path — FMA chain ascending in k:
        // acc = c0*x0; acc = fma(c1,x1,acc); acc = fma(c2,x2,acc)
        float dot = __fmul_rn(cx, x);
        dot = __fmaf_rn(cy, y, dot);
        dot = __fmaf_rn(cz, z, dot);
        // d2 = (cn - 2*dot) + xn   (elementwise A - B + C, left to right, no FMA)
        float d2  = __fadd_rn(__fsub_rn(cn, __fmul_rn(2.0f, dot)), xn);
        unsigned long long k =
            ((unsigned long long)fxform(__float_as_uint(d2)) << 32) | (unsigned)p;
        keys[i] = k;
        if (k < lmin) lmin = k;
    }

    __shared__ unsigned long long part[2][K2_WAVES];
    __shared__ unsigned nlist[GSIZE];
    const int wid  = tid >> 6;
    const int lane = tid & 63;

    for (int r = 0; r < GSIZE; ++r) {
        unsigned long long k = lmin;
#pragma unroll
        for (int off = 32; off >= 1; off >>= 1) {
            unsigned long long o = __shfl_xor(k, off, 64);
            if (o < k) k = o;
        }
        if (lane == 0) part[r & 1][wid] = k;
        __syncthreads();
#pragma unroll
        for (int w = 0; w < K2_WAVES; ++w) {
            unsigned long long o = part[r & 1][w];
            if (o < k) k = o;
        }
        if (tid == 0) nlist[r] = (unsigned)(k & 0xFFFFFFFFull);
        if (k == lmin) {   // exactly one thread wins (keys unique)
            lmin = ~0ull;
#pragma unroll
            for (int i = 0; i < K2_PPT; ++i) {
                if (keys[i] == k) keys[i] = ~0ull;
                if (keys[i] < lmin) lmin = keys[i];
            }
        }
    }
    __syncthreads();

    // ---- outputs ----
    const int OFF1 = N_B * NGROUP * GSIZE * 3;   // 393216 (neigh_attr)
    const int OFF2 = 2 * OFF1;                    // 786432 (center)
    const int OFF3 = OFF2 + N_B * NGROUP * 3;     // 798720 (center_attribute)

    if (tid < GSIZE) {
        unsigned p = nlist[tid];
        float x  = base[p * 6 + 0];
        float y  = base[p * 6 + 1];
        float z  = base[p * 6 + 2];
        float a0 = base[p * 6 + 3];
        float a1 = base[p * 6 + 4];
        float a2 = base[p * 6 + 5];
        size_t o = ((size_t)(b * NGROUP + g) * GSIZE + tid) * 3;
        out[o + 0] = __fsub_rn(x, cx);
        out[o + 1] = __fsub_rn(y, cy);
        out[o + 2] = __fsub_rn(z, cz);
        out[OFF1 + o + 0] = a0;
        out[OFF1 + o + 1] = a1;
        out[OFF1 + o + 2] = a2;
    } else if (tid == GSIZE) {
        size_t o = (size_t)(b * NGROUP + g) * 3;
        out[OFF2 + o + 0] = cx;
        out[OFF2 + o + 1] = cy;
        out[OFF2 + o + 2] = cz;
        out[OFF3 + o + 0] = base[qq * 6 + 3];
        out[OFF3 + o + 1] = base[qq * 6 + 4];
        out[OFF3 + o + 2] = base[qq * 6 + 5];
    }
}

extern "C" void kernel_launch(void* const* d_in, const int* in_sizes, int n_in,
                              void* d_out, int out_size, void* d_ws, size_t ws_size,
                              hipStream_t stream) {
    const float* xyz = (const float*)d_in[0];
    float* out = (float*)d_out;
    int* fps_idx = (int*)d_ws;   // 8*512 ints = 16 KB

    fps_kernel<<<N_B, K1_THREADS, 0, stream>>>(xyz, fps_idx);
    knn_kernel<<<N_B * NGROUP, K2_THREADS, 0, stream>>>(xyz, fps_idx, out);
}

// Round 3
// 826.766 us; speedup vs baseline: 1.1138x; 1.1138x over previous
//
#include <hip/hip_runtime.h>
#include <stdint.h>

#define N_PTS 8192
#define N_B 8
#define NGROUP 512
#define GSIZE 32
#define BIGF 1e10f

#define K1_THREADS 512
#define K1_PPT (N_PTS / K1_THREADS)   // 16
#define K1_WAVES (K1_THREADS / 64)    // 8

#define K2_THREADS 256
#define K2_PPT (N_PTS / K2_THREADS)   // 32
#define K2_WAVES (K2_THREADS / 64)    // 4

// ---------------- DPP wave64 reductions (gfx9 idiom, result valid in lane 63) --------
// row_shr:1,2,4,8 then row_bcast15 (row_mask 0xA), row_bcast31 (row_mask 0xC).
// bound_ctrl=false with old=src => invalid-source lanes keep old value (identity).

#define DPP_RED_STEP_F(ctrl, rmask, op)                                            \
    v = op(v, __int_as_float(__builtin_amdgcn_update_dpp(                          \
            __float_as_int(v), __float_as_int(v), ctrl, rmask, 0xF, false)))

__device__ __forceinline__ float wave_fmax(float v) {
    DPP_RED_STEP_F(0x111, 0xF, fmaxf);
    DPP_RED_STEP_F(0x112, 0xF, fmaxf);
    DPP_RED_STEP_F(0x114, 0xF, fmaxf);
    DPP_RED_STEP_F(0x118, 0xF, fmaxf);
    DPP_RED_STEP_F(0x142, 0xA, fmaxf);
    DPP_RED_STEP_F(0x143, 0xC, fmaxf);
    return v;   // lane 63 holds the wave max
}

#define DPP_RED_STEP_U(ctrl, rmask)                                                \
    { unsigned t = (unsigned)__builtin_amdgcn_update_dpp(                          \
            (int)v, (int)v, ctrl, rmask, 0xF, false);                              \
      v = (t < v) ? t : v; }

__device__ __forceinline__ unsigned wave_umin(unsigned v) {
    DPP_RED_STEP_U(0x111, 0xF);
    DPP_RED_STEP_U(0x112, 0xF);
    DPP_RED_STEP_U(0x114, 0xF);
    DPP_RED_STEP_U(0x118, 0xF);
    DPP_RED_STEP_U(0x142, 0xA);
    DPP_RED_STEP_U(0x143, 0xC);
    return v;   // lane 63 holds the wave min
}

__device__ __forceinline__ int rdlane63_i(int v) {
    return __builtin_amdgcn_readlane(v, 63);
}

// Exact (no-FMA) squared distance in numpy's evaluation order: (dx^2 + dy^2) + dz^2
__device__ __forceinline__ float sq_dist(float x, float y, float z,
                                         float cx, float cy, float cz) {
    float dx = __fsub_rn(x, cx);
    float dy = __fsub_rn(y, cy);
    float dz = __fsub_rn(z, cz);
    return __fadd_rn(__fadd_rn(__fmul_rn(dx, dx), __fmul_rn(dy, dy)), __fmul_rn(dz, dz));
}

// order-preserving float->uint transform (handles possible tiny-negative d2)
__device__ __forceinline__ unsigned fxform(unsigned u) {
    return u ^ (unsigned)(((int)u >> 31) | 0x80000000);
}

// ---------------- Kernel 1: farthest point sampling, one block per batch ---------------
extern "C" __global__ __launch_bounds__(K1_THREADS) void fps_kernel(
    const float* __restrict__ xyz, int* __restrict__ fps_idx)
{
    const int b   = blockIdx.x;
    const int tid = threadIdx.x;
    const float* base = xyz + (size_t)b * N_PTS * 6;

    float px[K1_PPT], py[K1_PPT], pz[K1_PPT], dd[K1_PPT];
#pragma unroll
    for (int i = 0; i < K1_PPT; ++i) {
        int p = tid + i * K1_THREADS;
        px[i] = base[p * 6 + 0];
        py[i] = base[p * 6 + 1];
        pz[i] = base[p * 6 + 2];
        dd[i] = BIGF;
    }

    __shared__ unsigned long long part[2][K1_WAVES];

    const int wid  = tid >> 6;
    const int lane = tid & 63;
    int cur = 0;

    for (int it = 0; it < NGROUP; ++it) {
        if (tid == 0) fps_idx[b * NGROUP + it] = cur;
        if (it == NGROUP - 1) break;

        // centroid = pts[cur] (wave-uniform scalar load)
        const int c = __builtin_amdgcn_readfirstlane(cur);
        const float cx = base[c * 6 + 0];
        const float cy = base[c * 6 + 1];
        const float cz = base[c * 6 + 2];

        // min-update + local argmax (first-max tie-break: strict >, ascending i)
        float bestd = -1.0f;
        int   besti = 0;
#pragma unroll
        for (int i = 0; i < K1_PPT; ++i) {
            float d = sq_dist(px[i], py[i], pz[i], cx, cy, cz);
            dd[i] = fminf(dd[i], d);
            if (dd[i] > bestd) { bestd = dd[i]; besti = i; }
        }
        unsigned bestp = (unsigned)(tid + (besti << 9));   // besti*K1_THREADS

        // wave argmax, exact tie-break: phase 1 = max dist (DPP), phase 2 = min idx among tied
        float wm = __int_as_float(rdlane63_i(__float_as_int(wave_fmax(bestd))));
        unsigned cand = (bestd == wm) ? bestp : 0xFFFFFFFFu;
        unsigned wi = (unsigned)rdlane63_i((int)wave_umin(cand));

        if (lane == 0)
            part[it & 1][wid] = ((unsigned long long)__float_as_uint(wm) << 32)
                              | (unsigned long long)(0xFFFFFFFFu - wi);
        __syncthreads();

        unsigned long long key = 0;
#pragma unroll
        for (int w = 0; w < K1_WAVES; ++w) {
            unsigned long long o = part[it & 1][w];
            if (o > key) key = o;
        }
        cur = (int)(0xFFFFFFFFu - (unsigned)(key & 0xFFFFFFFFull));
    }
}

// ---------------- Kernel 2: 32-NN per (batch, group) + gather/write outputs -----------
extern "C" __global__ __launch_bounds__(K2_THREADS) void knn_kernel(
    const float* __restrict__ xyz, const int* __restrict__ fps_idx,
    float* __restrict__ out)
{
    const int bg  = blockIdx.x;
    const int b   = bg >> 9;          // / NGROUP
    const int g   = bg & (NGROUP - 1);
    const int tid = threadIdx.x;
    const float* base = xyz + (size_t)b * N_PTS * 6;

    const int q  = fps_idx[b * NGROUP + g];
    const int qq = __builtin_amdgcn_readfirstlane(q);
    const float cx = base[qq * 6 + 0];
    const float cy = base[qq * 6 + 1];
    const float cz = base[qq * 6 + 2];
    // ||c||^2: separate square, left-assoc add, NO FMA
    const float cn = __fadd_rn(__fadd_rn(__fmul_rn(cx, cx), __fmul_rn(cy, cy)),
                               __fmul_rn(cz, cz));

    unsigned long long keys[K2_PPT];
    unsigned long long lmin = ~0ull;
#pragma unroll
    for (int i = 0; i < K2_PPT; ++i) {
        int p = tid + i * K2_THREADS;
        float x = base[p * 6 + 0];
        float y = base[p * 6 + 1];
        float z = base[p * 6 + 2];
        // ||x||^2: NO FMA (separate numpy op)
        float xn  = __fadd_rn(__fadd_rn(__fmul_rn(x, x), __fmul_rn(y, y)), __fmul_rn(z, z));
        // einsum dot: FMA chain ascending in k (XLA dot path)
        float dot = __fmul_rn(cx, x);
        dot = __fmaf_rn(cy, y, dot);
        dot = __fmaf_rn(cz, z, dot);
        // d2 = (cn - 2*dot) + xn   (left to right, no FMA)
        float d2  = __fadd_rn(__fsub_rn(cn, __fmul_rn(2.0f, dot)), xn);
        unsigned long long k =
            ((unsigned long long)fxform(__float_as_uint(d2)) << 32) | (unsigned)p;
        keys[i] = k;
        if (k < lmin) lmin = k;
    }

    __shared__ unsigned long long part[2][K2_WAVES];
    __shared__ unsigned nlist[GSIZE];
    const int wid  = tid >> 6;
    const int lane = tid & 63;

    for (int r = 0; r < GSIZE; ++r) {
        // wave min of u64 key, two-phase DPP: min hi (d2 bits), then min lo (idx) among tied
        unsigned hi = (unsigned)(lmin >> 32);
        unsigned lo = (unsigned)(lmin & 0xFFFFFFFFull);
        unsigned wh = (unsigned)rdlane63_i((int)wave_umin(hi));
        unsigned cand = (hi == wh) ? lo : 0xFFFFFFFFu;
        unsigned wl = (unsigned)rdlane63_i((int)wave_umin(cand));
        unsigned long long k = ((unsigned long long)wh << 32) | wl;

        if (lane == 0) part[r & 1][wid] = k;
        __syncthreads();
#pragma unroll
        for (int w = 0; w < K2_WAVES; ++w) {
            unsigned long long o = part[r & 1][w];
            if (o < k) k = o;
        }
        if (tid == 0) nlist[r] = (unsigned)(k & 0xFFFFFFFFull);
        if (k == lmin) {   // exactly one thread wins (keys unique)
            lmin = ~0ull;
#pragma unroll
            for (int i = 0; i < K2_PPT; ++i) {
                if (keys[i] == k) keys[i] = ~0ull;
                if (keys[i] < lmin) lmin = keys[i];
            }
        }
    }
    __syncthreads();

    // ---- outputs ----
    const int OFF1 = N_B * NGROUP * GSIZE * 3;   // 393216 (neigh_attr)
    const int OFF2 = 2 * OFF1;                    // 786432 (center)
    const int OFF3 = OFF2 + N_B * NGROUP * 3;     // 798720 (center_attribute)

    if (tid < GSIZE) {
        unsigned p = nlist[tid];
        float x  = base[p * 6 + 0];
        float y  = base[p * 6 + 1];
        float z  = base[p * 6 + 2];
        float a0 = base[p * 6 + 3];
        float a1 = base[p * 6 + 4];
        float a2 = base[p * 6 + 5];
        size_t o = ((size_t)(b * NGROUP + g) * GSIZE + tid) * 3;
        out[o + 0] = __fsub_rn(x, cx);
        out[o + 1] = __fsub_rn(y, cy);
        out[o + 2] = __fsub_rn(z, cz);
        out[OFF1 + o + 0] = a0;
        out[OFF1 + o + 1] = a1;
        out[OFF1 + o + 2] = a2;
    } else if (tid == GSIZE) {
        size_t o = (size_t)(b * NGROUP + g) * 3;
        out[OFF2 + o + 0] = cx;
        out[OFF2 + o + 1] = cy;
        out[OFF2 + o + 2] = cz;
        out[OFF3 + o + 0] = base[qq * 6 + 3];
        out[OFF3 + o + 1] = base[qq * 6 + 4];
        out[OFF3 + o + 2] = base[qq * 6 + 5];
    }
}

extern "C" void kernel_launch(void* const* d_in, const int* in_sizes, int n_in,
                              void* d_out, int out_size, void* d_ws, size_t ws_size,
                              hipStream_t stream) {
    const float* xyz = (const float*)d_in[0];
    float* out = (float*)d_out;
    int* fps_idx = (int*)d_ws;   // 8*512 ints = 16 KB

    fps_kernel<<<N_B, K1_THREADS, 0, stream>>>(xyz, fps_idx);
    knn_kernel<<<N_B * NGROUP, K2_THREADS, 0, stream>>>(xyz, fps_idx, out);
}

// Round 4
// 759.231 us; speedup vs baseline: 1.2128x; 1.0890x over previous
//
#include <hip/hip_runtime.h>
#include <stdint.h>

#define N_PTS 8192
#define N_B 8
#define NGROUP 512
#define GSIZE 32
#define BIGF 1e10f

#define K1_THREADS 512
#define K1_PPT (N_PTS / K1_THREADS)   // 16
#define K1_WAVES (K1_THREADS / 64)    // 8

#define K2_THREADS 256
#define K2_PPT (N_PTS / K2_THREADS)   // 32
#define K2_WAVES (K2_THREADS / 64)    // 4

// ---------------- DPP wave64 reductions (gfx9 idiom, result valid in lane 63) --------
#define DPP_RED_STEP_F(ctrl, rmask, op)                                            \
    v = op(v, __int_as_float(__builtin_amdgcn_update_dpp(                          \
            __float_as_int(v), __float_as_int(v), ctrl, rmask, 0xF, false)))

__device__ __forceinline__ float wave_fmax(float v) {
    DPP_RED_STEP_F(0x111, 0xF, fmaxf);
    DPP_RED_STEP_F(0x112, 0xF, fmaxf);
    DPP_RED_STEP_F(0x114, 0xF, fmaxf);
    DPP_RED_STEP_F(0x118, 0xF, fmaxf);
    DPP_RED_STEP_F(0x142, 0xA, fmaxf);
    DPP_RED_STEP_F(0x143, 0xC, fmaxf);
    return v;   // lane 63 holds the wave max
}

#define DPP_RED_STEP_U(ctrl, rmask)                                                \
    { unsigned t = (unsigned)__builtin_amdgcn_update_dpp(                          \
            (int)v, (int)v, ctrl, rmask, 0xF, false);                              \
      v = (t < v) ? t : v; }

__device__ __forceinline__ unsigned wave_umin(unsigned v) {
    DPP_RED_STEP_U(0x111, 0xF);
    DPP_RED_STEP_U(0x112, 0xF);
    DPP_RED_STEP_U(0x114, 0xF);
    DPP_RED_STEP_U(0x118, 0xF);
    DPP_RED_STEP_U(0x142, 0xA);
    DPP_RED_STEP_U(0x143, 0xC);
    return v;   // lane 63 holds the wave min
}

__device__ __forceinline__ int rdlane63_i(int v) {
    return __builtin_amdgcn_readlane(v, 63);
}

// u64 max across lanes 0..7 of each 16-lane row (inputs replicated part[lane&7]);
// result valid in lane 7 (and 15, etc.)
#define U64_MAX_STEP(ctrl)                                                         \
    { unsigned lo = (unsigned)v, hi = (unsigned)(v >> 32);                         \
      unsigned olo = (unsigned)__builtin_amdgcn_update_dpp((int)lo, (int)lo, ctrl, 0xF, 0xF, false); \
      unsigned ohi = (unsigned)__builtin_amdgcn_update_dpp((int)hi, (int)hi, ctrl, 0xF, 0xF, false); \
      unsigned long long o = ((unsigned long long)ohi << 32) | olo;                \
      if (o > v) v = o; }

__device__ __forceinline__ unsigned long long row8_u64_max(unsigned long long v) {
    U64_MAX_STEP(0x111);  // row_shr:1
    U64_MAX_STEP(0x112);  // row_shr:2
    U64_MAX_STEP(0x114);  // row_shr:4
    return v;             // lane 7 of each row holds max of part[0..7]
}

// Exact (no-FMA) squared distance in numpy's evaluation order: (dx^2 + dy^2) + dz^2
__device__ __forceinline__ float sq_dist(float x, float y, float z,
                                         float cx, float cy, float cz) {
    float dx = __fsub_rn(x, cx);
    float dy = __fsub_rn(y, cy);
    float dz = __fsub_rn(z, cz);
    return __fadd_rn(__fadd_rn(__fmul_rn(dx, dx), __fmul_rn(dy, dy)), __fmul_rn(dz, dz));
}

// order-preserving float->uint transform (handles possible tiny-negative d2)
__device__ __forceinline__ unsigned fxform(unsigned u) {
    return u ^ (unsigned)(((int)u >> 31) | 0x80000000);
}

// ---------------- Kernel 1: farthest point sampling, one block per batch ---------------
extern "C" __global__ __launch_bounds__(K1_THREADS) void fps_kernel(
    const float* __restrict__ xyz, int* __restrict__ fps_idx)
{
    const int b   = blockIdx.x;
    const int tid = threadIdx.x;
    const float* base = xyz + (size_t)b * N_PTS * 6;

    __shared__ float lx[N_PTS], ly[N_PTS], lz[N_PTS];
    __shared__ unsigned long long part8[2][K1_WAVES];

    float px[K1_PPT], py[K1_PPT], pz[K1_PPT], dd[K1_PPT];
#pragma unroll
    for (int i = 0; i < K1_PPT; ++i) {
        int p = tid + i * K1_THREADS;
        px[i] = base[p * 6 + 0];
        py[i] = base[p * 6 + 1];
        pz[i] = base[p * 6 + 2];
        dd[i] = BIGF;
        lx[p] = px[i]; ly[p] = py[i]; lz[p] = pz[i];
    }
    __syncthreads();

    const int lane = tid & 63;
    const int wid  = tid >> 6;
    int cur = 0;

    for (int it = 0; it < NGROUP; ++it) {
        if (tid == 0) fps_idx[b * NGROUP + it] = cur;
        if (it == NGROUP - 1) break;

        // centroid from LDS (uniform broadcast read)
        const int c = __builtin_amdgcn_readfirstlane(cur);
        const float cx = lx[c];
        const float cy = ly[c];
        const float cz = lz[c];

        // pure min-update (no index tracking: independent chains, 9 instr/pt)
#pragma unroll
        for (int i = 0; i < K1_PPT; ++i) {
            float d = sq_dist(px[i], py[i], pz[i], cx, cy, cz);
            dd[i] = fminf(dd[i], d);
        }
        // thread-local max (compiler folds to v_max3 tree)
        float bestd = dd[0];
#pragma unroll
        for (int i = 1; i < K1_PPT; ++i) bestd = fmaxf(bestd, dd[i]);

        // wave max
        float wm = __int_as_float(rdlane63_i(__float_as_int(wave_fmax(bestd))));

        // post-scan: smallest local slot i with dd[i]==wm (descending overwrite)
        int ii = K1_PPT;
#pragma unroll
        for (int i = K1_PPT - 1; i >= 0; --i) if (dd[i] == wm) ii = i;
        unsigned cand = (ii < K1_PPT) ? (unsigned)(tid + (ii << 9)) : 0xFFFFFFFFu;

        // wave min index among tied lanes; fast path when a single lane matches
        unsigned long long bal = __ballot(cand != 0xFFFFFFFFu);
        unsigned wi;
        if (__popcll(bal) == 1) {
            int l = (int)(__ffsll((long long)bal) - 1);
            wi = (unsigned)__builtin_amdgcn_readlane((int)cand, l);
        } else {
            wi = (unsigned)rdlane63_i((int)wave_umin(cand));
        }

        if (lane == 0)
            part8[it & 1][wid] = ((unsigned long long)__float_as_uint(wm) << 32)
                               | (unsigned long long)(0xFFFFFFFFu - wi);
        __syncthreads();

        // block max of 8 partials via 3-step DPP u64 max (lanes read part8[lane&7])
        unsigned long long v = part8[it & 1][lane & 7];
        v = row8_u64_max(v);
        unsigned klo = (unsigned)__builtin_amdgcn_readlane((int)(unsigned)v, 7);
        cur = (int)(0xFFFFFFFFu - klo);
    }
}

// ---------------- Kernel 2: 32-NN per (batch, group) + gather/write outputs -----------
extern "C" __global__ __launch_bounds__(K2_THREADS) void knn_kernel(
    const float* __restrict__ xyz, const int* __restrict__ fps_idx,
    float* __restrict__ out)
{
    const int bg  = blockIdx.x;
    const int b   = bg >> 9;          // / NGROUP
    const int g   = bg & (NGROUP - 1);
    const int tid = threadIdx.x;
    const float* base = xyz + (size_t)b * N_PTS * 6;

    const int q  = fps_idx[b * NGROUP + g];
    const int qq = __builtin_amdgcn_readfirstlane(q);
    const float cx = base[qq * 6 + 0];
    const float cy = base[qq * 6 + 1];
    const float cz = base[qq * 6 + 2];
    // ||c||^2: separate square, left-assoc add, NO FMA
    const float cn = __fadd_rn(__fadd_rn(__fmul_rn(cx, cx), __fmul_rn(cy, cy)),
                               __fmul_rn(cz, cz));

    unsigned long long keys[K2_PPT];
    unsigned long long lmin = ~0ull;
#pragma unroll
    for (int i = 0; i < K2_PPT; ++i) {
        int p = tid + i * K2_THREADS;
        float x = base[p * 6 + 0];
        float y = base[p * 6 + 1];
        float z = base[p * 6 + 2];
        // ||x||^2: NO FMA (separate numpy op)
        float xn  = __fadd_rn(__fadd_rn(__fmul_rn(x, x), __fmul_rn(y, y)), __fmul_rn(z, z));
        // einsum dot: FMA chain ascending in k (XLA dot path)
        float dot = __fmul_rn(cx, x);
        dot = __fmaf_rn(cy, y, dot);
        dot = __fmaf_rn(cz, z, dot);
        // d2 = (cn - 2*dot) + xn   (left to right, no FMA)
        float d2  = __fadd_rn(__fsub_rn(cn, __fmul_rn(2.0f, dot)), xn);
        unsigned long long k =
            ((unsigned long long)fxform(__float_as_uint(d2)) << 32) | (unsigned)p;
        keys[i] = k;
        if (k < lmin) lmin = k;
    }

    __shared__ unsigned long long part[2][K2_WAVES];
    __shared__ unsigned nlist[GSIZE];
    const int wid  = tid >> 6;
    const int lane = tid & 63;

    for (int r = 0; r < GSIZE; ++r) {
        // wave min of u64 key: min hi (d2 bits); index via readlane if unique, else DPP min
        unsigned hi = (unsigned)(lmin >> 32);
        unsigned lo = (unsigned)(lmin & 0xFFFFFFFFull);
        unsigned wh = (unsigned)rdlane63_i((int)wave_umin(hi));
        unsigned long long bal = __ballot(hi == wh);
        unsigned wl;
        if (__popcll(bal) == 1) {
            int l = (int)(__ffsll((long long)bal) - 1);
            wl = (unsigned)__builtin_amdgcn_readlane((int)lo, l);
        } else {
            unsigned cand = (hi == wh) ? lo : 0xFFFFFFFFu;
            wl = (unsigned)rdlane63_i((int)wave_umin(cand));
        }
        unsigned long long k = ((unsigned long long)wh << 32) | wl;

        if (lane == 0) part[r & 1][wid] = k;
        __syncthreads();
#pragma unroll
        for (int w = 0; w < K2_WAVES; ++w) {
            unsigned long long o = part[r & 1][w];
            if (o < k) k = o;
        }
        if (tid == 0) nlist[r] = (unsigned)(k & 0xFFFFFFFFull);
        if (k == lmin) {   // exactly one thread wins (keys unique)
            lmin = ~0ull;
#pragma unroll
            for (int i = 0; i < K2_PPT; ++i) {
                if (keys[i] == k) keys[i] = ~0ull;
                if (keys[i] < lmin) lmin = keys[i];
            }
        }
    }
    __syncthreads();

    // ---- outputs ----
    const int OFF1 = N_B * NGROUP * GSIZE * 3;   // 393216 (neigh_attr)
    const int OFF2 = 2 * OFF1;                    // 786432 (center)
    const int OFF3 = OFF2 + N_B * NGROUP * 3;     // 798720 (center_attribute)

    if (tid < GSIZE) {
        unsigned p = nlist[tid];
        float x  = base[p * 6 + 0];
        float y  = base[p * 6 + 1];
        float z  = base[p * 6 + 2];
        float a0 = base[p * 6 + 3];
        float a1 = base[p * 6 + 4];
        float a2 = base[p * 6 + 5];
        size_t o = ((size_t)(b * NGROUP + g) * GSIZE + tid) * 3;
        out[o + 0] = __fsub_rn(x, cx);
        out[o + 1] = __fsub_rn(y, cy);
        out[o + 2] = __fsub_rn(z, cz);
        out[OFF1 + o + 0] = a0;
        out[OFF1 + o + 1] = a1;
        out[OFF1 + o + 2] = a2;
    } else if (tid == GSIZE) {
        size_t o = (size_t)(b * NGROUP + g) * 3;
        out[OFF2 + o + 0] = cx;
        out[OFF2 + o + 1] = cy;
        out[OFF2 + o + 2] = cz;
        out[OFF3 + o + 0] = base[qq * 6 + 3];
        out[OFF3 + o + 1] = base[qq * 6 + 4];
        out[OFF3 + o + 2] = base[qq * 6 + 5];
    }
}

extern "C" void kernel_launch(void* const* d_in, const int* in_sizes, int n_in,
                              void* d_out, int out_size, void* d_ws, size_t ws_size,
                              hipStream_t stream) {
    const float* xyz = (const float*)d_in[0];
    float* out = (float*)d_out;
    int* fps_idx = (int*)d_ws;   // 8*512 ints = 16 KB

    fps_kernel<<<N_B, K1_THREADS, 0, stream>>>(xyz, fps_idx);
    knn_kernel<<<N_B * NGROUP, K2_THREADS, 0, stream>>>(xyz, fps_idx, out);
}